// Round 5
// baseline (93.504 us; speedup 1.0000x reference)
//
#include <hip/hip_runtime.h>
#include <math.h>

#define H 1024
#define T 4096
#define B 16

typedef float f4 __attribute__((ext_vector_type(4)));

// ws layout: v[B*H] floats | scores[B*T] floats | cnt[B*32] ints

// Kernel 1: v[b,h] = sum_d dec[d,b] * W[d,h]  (v = dec^T @ W, 16x1024)
// 512 blocks = 16 b x 32 htiles (32 h each); 2 blocks/CU. Block: 256 thr =
// 32 dc (d-chunks of 32) x 8 h4 (f4 groups); LDS tree-reduce over dc.
// Also zeroes the per-b completion counters for kernel 2.
__global__ void __launch_bounds__(256) proj_vec_kernel(
    const float* __restrict__ dec, const float* __restrict__ W,
    float* __restrict__ v, int* __restrict__ cnt)
{
    if (blockIdx.x == 0 && threadIdx.x < B) cnt[threadIdx.x * 32] = 0;

    int b      = blockIdx.x >> 5;
    int htile  = blockIdx.x & 31;
    int h4     = threadIdx.x & 7;
    int dc     = threadIdx.x >> 3;
    int h4base = htile * 8;

    const f4* Wp = (const f4*)W;
    f4 acc = {0.f, 0.f, 0.f, 0.f};
    int d0 = dc * 32;
    #pragma unroll 8
    for (int i = 0; i < 32; ++i) {
        int d = d0 + i;
        float s = dec[d * B + b];
        f4 w = Wp[d * (H / 4) + h4base + h4];
        acc += s * w;
    }

    __shared__ f4 red[256];
    red[threadIdx.x] = acc;          // layout [dc][h4]
    __syncthreads();
    #pragma unroll
    for (int s = 16; s > 0; s >>= 1) {
        if (dc < s) {
            f4 m = red[dc * 8 + h4] + red[(dc + s) * 8 + h4];
            red[dc * 8 + h4] = m;
        }
        __syncthreads();
    }
    if (dc == 0)
        ((f4*)(v + b * H))[h4base + h4] = red[h4];
}

// Kernel 2: scores[b,t] = dot(v[b,:], enc[t,b,:]), then the LAST block to
// finish each b's 4096 scores runs that row's softmax in-kernel.
// Main path identical to the proven R3 shape: one wave per (t,b), 4x f4
// nontemporal enc loads, contiguous 16 KiB per block.
// Visibility chain: score stores are device-scope relaxed atomic stores
// (write-through to the coherence point); __syncthreads() drains vmcnt so
// they are committed before the check-in atomicAdd; counter==T implies all
// 4096 rows' stores are globally visible; finisher's lines were never
// cached locally (nobody reads scores earlier), so plain loads are fresh.
__global__ void __launch_bounds__(256) scores_softmax_kernel(
    const float* __restrict__ v, const float* __restrict__ enc,
    float* scores, int* cnt, float* out)
{
    int wave = (int)((blockIdx.x * 256u + threadIdx.x) >> 6);  // 0..65535
    int lane = threadIdx.x & 63;
    int b = wave & (B - 1);
    int t = wave >> 4;

    const f4* ep = (const f4*)(enc + (size_t)t * (B * H) + (size_t)b * H);
    const f4* vp = (const f4*)(v + b * H);
    float acc = 0.f;
    #pragma unroll
    for (int i = 0; i < 4; ++i) {
        f4 e = __builtin_nontemporal_load(&ep[lane + i * 64]);
        f4 w = vp[lane + i * 64];
        acc = fmaf(e.x, w.x, acc);
        acc = fmaf(e.y, w.y, acc);
        acc = fmaf(e.z, w.z, acc);
        acc = fmaf(e.w, w.w, acc);
    }
    #pragma unroll
    for (int off = 32; off > 0; off >>= 1)
        acc += __shfl_down(acc, off);

    if (lane == 0)
        __hip_atomic_store(&scores[(size_t)b * T + t], acc,
                           __ATOMIC_RELAXED, __HIP_MEMORY_SCOPE_AGENT);

    __syncthreads();   // drains vmcnt(0): all 4 score stores committed

    if (threadIdx.x < 64) {            // wave 0 checks in for the block
        int last = 0;
        if (lane < 4) {
            int bb = (blockIdx.x * 4 + lane) & (B - 1);
            int old = atomicAdd(&cnt[bb * 32], 1);
            last = (old == T - 1);
        }
        unsigned long long mask = __ballot(last);
        while (mask) {
            int p = __ffsll(mask) - 1;
            mask &= mask - 1;
            int bb = (blockIdx.x * 4 + p) & (B - 1);

            // wave-wide online softmax of scores[bb, 0..T-1]
            const f4* rp = (const f4*)(scores + (size_t)bb * T);
            float m = -INFINITY, s = 0.f;
            #pragma unroll 4
            for (int i = 0; i < 16; ++i) {
                f4 x = rp[lane + i * 64];
                float xm = fmaxf(fmaxf(x.x, x.y), fmaxf(x.z, x.w));
                float mn = fmaxf(m, xm);
                s = s * __expf(m - mn)
                    + __expf(x.x - mn) + __expf(x.y - mn)
                    + __expf(x.z - mn) + __expf(x.w - mn);
                m = mn;
            }
            #pragma unroll
            for (int off = 32; off > 0; off >>= 1) {
                float mo = __shfl_xor(m, off);
                float so = __shfl_xor(s, off);
                float mn = fmaxf(m, mo);
                s = s * __expf(m - mn) + so * __expf(mo - mn);
                m = mn;
            }
            float inv = 1.f / s;

            asm volatile("" ::: "memory");  // forbid load-CSE with pass 1

            f4* op = (f4*)(out + (size_t)bb * T);
            #pragma unroll 4
            for (int i = 0; i < 16; ++i) {
                f4 x = rp[lane + i * 64];
                f4 r;
                r.x = __expf(x.x - m) * inv;
                r.y = __expf(x.y - m) * inv;
                r.z = __expf(x.z - m) * inv;
                r.w = __expf(x.w - m) * inv;
                op[lane + i * 64] = r;
            }
        }
    }
}

extern "C" void kernel_launch(void* const* d_in, const int* in_sizes, int n_in,
                              void* d_out, int out_size, void* d_ws, size_t ws_size,
                              hipStream_t stream)
{
    const float* dec = (const float*)d_in[0];   // [H, B]
    const float* enc = (const float*)d_in[1];   // [T, B, H]
    const float* W   = (const float*)d_in[2];   // [H, H]
    float* out = (float*)d_out;                 // [B, T]

    float* v      = (float*)d_ws;               // B*H floats
    float* scores = v + B * H;                  // B*T floats
    int*   cnt    = (int*)(scores + B * T);     // B*32 ints (128B-strided)

    proj_vec_kernel<<<512, 256, 0, stream>>>(dec, W, v, cnt);
    scores_softmax_kernel<<<(T * B) / 4, 256, 0, stream>>>(v, enc, scores, cnt, out);
}

// Round 6
// 62.053 us; speedup vs baseline: 1.5068x; 1.5068x over previous
//
#include <hip/hip_runtime.h>
#include <math.h>

#define H 1024
#define T 4096
#define B 16

typedef float f4 __attribute__((ext_vector_type(4)));

// ws layout: v[B*H] f32 (64 KB) | cnt1[128*16] int (8 KB) | cnt2[16*16] int (1 KB)
// cnt1: 16 b x 8 spread first-level counters, one 64B line each (bucket = 512).
// cnt2: per-b second-level counter (8 buckets).

// Kernel 1: v[b,h] = sum_d dec[d,b] * W[d,h]  (v = dec^T @ W, 16x1024)
// 512 blocks = 16 b x 32 htiles; 32 dc x 8 h4 per block; LDS tree reduce.
// Block 0 also zeroes the completion counters for kernel 2.
__global__ void __launch_bounds__(256) proj_vec_kernel(
    const float* __restrict__ dec, const float* __restrict__ W,
    float* __restrict__ v, int* __restrict__ cnt1, int* __restrict__ cnt2)
{
    if (blockIdx.x == 0) {
        if (threadIdx.x < 128)      cnt1[threadIdx.x * 16] = 0;
        else if (threadIdx.x < 144) cnt2[(threadIdx.x - 128) * 16] = 0;
    }

    int b      = blockIdx.x >> 5;
    int htile  = blockIdx.x & 31;
    int h4     = threadIdx.x & 7;
    int dc     = threadIdx.x >> 3;
    int h4base = htile * 8;

    const f4* Wp = (const f4*)W;
    f4 acc = {0.f, 0.f, 0.f, 0.f};
    int d0 = dc * 32;
    #pragma unroll 8
    for (int i = 0; i < 32; ++i) {
        int d = d0 + i;
        float s = dec[d * B + b];
        f4 w = Wp[d * (H / 4) + h4base + h4];
        acc += s * w;
    }

    __shared__ f4 red[256];
    red[threadIdx.x] = acc;          // [dc][h4]
    __syncthreads();
    #pragma unroll
    for (int s = 16; s > 0; s >>= 1) {
        if (dc < s) {
            f4 m = red[dc * 8 + h4] + red[(dc + s) * 8 + h4];
            red[dc * 8 + h4] = m;
        }
        __syncthreads();
    }
    if (dc == 0)
        ((f4*)(v + b * H))[h4base + h4] = red[h4];
}

// Kernel 2: scores[b,t] = dot(v[b,:], enc[t,b,:]) written to out[b,t]
// (agent-scope stores), then the last block to complete each b runs a
// block-wide in-place softmax of that row.
// Main path identical to the proven R3 shape: one wave per (t,b), 4x f4
// nontemporal enc loads, block covers 16 KiB contiguous of enc.
__global__ void __launch_bounds__(256) scores_softmax_kernel(
    const float* __restrict__ v, const float* __restrict__ enc,
    int* cnt1, int* cnt2, float* out)
{
    int tid  = threadIdx.x;
    int wave = (int)((blockIdx.x * 256u + tid) >> 6);  // 0..65535
    int lane = tid & 63;
    int b = wave & (B - 1);
    int t = wave >> 4;

    const f4* ep = (const f4*)(enc + (size_t)t * (B * H) + (size_t)b * H);
    const f4* vp = (const f4*)(v + b * H);
    float acc = 0.f;
    #pragma unroll
    for (int i = 0; i < 4; ++i) {
        f4 e = __builtin_nontemporal_load(&ep[lane + i * 64]);
        f4 w = vp[lane + i * 64];
        acc = fmaf(e.x, w.x, acc);
        acc = fmaf(e.y, w.y, acc);
        acc = fmaf(e.z, w.z, acc);
        acc = fmaf(e.w, w.w, acc);
    }
    #pragma unroll
    for (int off = 32; off > 0; off >>= 1)
        acc += __shfl_down(acc, off);

    if (lane == 0)
        __hip_atomic_store(&out[(size_t)b * T + t], acc,
                           __ATOMIC_RELAXED, __HIP_MEMORY_SCOPE_AGENT);

    __syncthreads();   // drains vmcnt: this block's 4 score stores committed

    // Check-in: lanes 0..3 of wave 0, one atomic per (block, owned b),
    // spread over 8 single-line counters per b to avoid same-line stalls.
    __shared__ unsigned long long finmask_sh;
    if (tid < 64) {
        int last = 0;
        if (lane < 4) {
            int bb = (blockIdx.x * 4 + lane) & (B - 1);
            int sp = (blockIdx.x >> 2) & 7;
            int old = atomicAdd(&cnt1[((bb << 3) | sp) * 16], 1);
            if (old == 511) {                       // bucket complete
                int old2 = atomicAdd(&cnt2[bb * 16], 1);
                last = (old2 == 7);                 // all 8 buckets done
            }
        }
        unsigned long long mask = __ballot(last);
        if (lane == 0) finmask_sh = mask;
    }
    __syncthreads();

    unsigned long long mask = finmask_sh;
    while (mask) {
        int p = __ffsll((unsigned long long)mask) - 1;
        mask &= mask - 1;
        int bb = (blockIdx.x * 4 + p) & (B - 1);

        // Block-wide in-place softmax of out[bb, 0..T-1].
        // Agent-scope loads: row lines may be stale in this XCD's L2
        // (written by other XCDs / previous replay) — bypass to coherence pt.
        float* row = out + (size_t)bb * T;
        __shared__ float red[8];
        float x[16];
        float m = -INFINITY;
        #pragma unroll
        for (int i = 0; i < 16; ++i) {
            x[i] = __hip_atomic_load(&row[tid + i * 256],
                                     __ATOMIC_RELAXED, __HIP_MEMORY_SCOPE_AGENT);
            m = fmaxf(m, x[i]);
        }
        #pragma unroll
        for (int off = 32; off > 0; off >>= 1)
            m = fmaxf(m, __shfl_xor(m, off));
        if (lane == 0) red[tid >> 6] = m;
        __syncthreads();
        m = fmaxf(fmaxf(red[0], red[1]), fmaxf(red[2], red[3]));

        float ssum = 0.f;
        #pragma unroll
        for (int i = 0; i < 16; ++i) {
            x[i] = __expf(x[i] - m);
            ssum += x[i];
        }
        #pragma unroll
        for (int off = 32; off > 0; off >>= 1)
            ssum += __shfl_xor(ssum, off);
        if (lane == 0) red[4 + (tid >> 6)] = ssum;
        __syncthreads();
        float inv = 1.f / (red[4] + red[5] + red[6] + red[7]);

        #pragma unroll
        for (int i = 0; i < 16; ++i)
            row[tid + i * 256] = x[i] * inv;
    }
}

extern "C" void kernel_launch(void* const* d_in, const int* in_sizes, int n_in,
                              void* d_out, int out_size, void* d_ws, size_t ws_size,
                              hipStream_t stream)
{
    const float* dec = (const float*)d_in[0];   // [H, B]
    const float* enc = (const float*)d_in[1];   // [T, B, H]
    const float* W   = (const float*)d_in[2];   // [H, H]
    float* out = (float*)d_out;                 // [B, T]

    float* v    = (float*)d_ws;                 // B*H floats
    int*   cnt1 = (int*)(v + B * H);            // 128 counters, 64B stride
    int*   cnt2 = cnt1 + 128 * 16;              // 16 counters, 64B stride

    proj_vec_kernel<<<512, 256, 0, stream>>>(dec, W, v, cnt1, cnt2);
    scores_softmax_kernel<<<(T * B) / 4, 256, 0, stream>>>(v, enc, cnt1, cnt2, out);
}

// Round 7
// 52.285 us; speedup vs baseline: 1.7883x; 1.1868x over previous
//
#include <hip/hip_runtime.h>
#include <math.h>

#define H 1024
#define T 4096
#define B 16

typedef float f4 __attribute__((ext_vector_type(4)));

// Kernel 1: v[b,h] = sum_d dec[d,b] * W[d,h]  (v = dec^T @ W, 16x1024)
// 512 blocks = 16 b x 32 htiles (32 h each); 2 blocks/CU -> 2 waves/SIMD.
// Block: 256 thr = 32 dc (d-chunks of 32) x 8 h4; LDS tree-reduce over dc.
__global__ void __launch_bounds__(256) proj_vec_kernel(
    const float* __restrict__ dec, const float* __restrict__ W,
    float* __restrict__ v)
{
    int b      = blockIdx.x >> 5;
    int htile  = blockIdx.x & 31;
    int h4     = threadIdx.x & 7;
    int dc     = threadIdx.x >> 3;
    int h4base = htile * 8;

    const f4* Wp = (const f4*)W;
    f4 acc = {0.f, 0.f, 0.f, 0.f};
    int d0 = dc * 32;
    #pragma unroll 8
    for (int i = 0; i < 32; ++i) {
        int d = d0 + i;
        float s = dec[d * B + b];
        f4 w = Wp[d * (H / 4) + h4base + h4];
        acc += s * w;
    }

    __shared__ f4 red[256];
    red[threadIdx.x] = acc;          // [dc][h4]
    __syncthreads();
    #pragma unroll
    for (int s = 16; s > 0; s >>= 1) {
        if (dc < s) {
            f4 m = red[dc * 8 + h4] + red[(dc + s) * 8 + h4];
            red[dc * 8 + h4] = m;
        }
        __syncthreads();
    }
    if (dc == 0)
        ((f4*)(v + b * H))[h4base + h4] = red[h4];
}

// Kernel 2: scores[b,t] = dot(v[b,:], enc[t,b,:])  — the proven R3 shape.
// One 64-lane wave per (t,b); 4x f4 nontemporal enc loads per lane; block
// of 4 waves covers 16 KiB contiguous of enc. Pure HBM stream.
__global__ void __launch_bounds__(256) scores_kernel(
    const float* __restrict__ v, const float* __restrict__ enc,
    float* __restrict__ scores)
{
    int wave = (int)((blockIdx.x * 256u + threadIdx.x) >> 6);  // 0..65535
    int lane = threadIdx.x & 63;
    int b = wave & (B - 1);
    int t = wave >> 4;
    const f4* ep = (const f4*)(enc + (size_t)t * (B * H) + (size_t)b * H);
    const f4* vp = (const f4*)(v + b * H);
    float acc = 0.f;
    #pragma unroll
    for (int i = 0; i < 4; ++i) {
        f4 e = __builtin_nontemporal_load(&ep[lane + i * 64]);
        f4 w = vp[lane + i * 64];
        acc = fmaf(e.x, w.x, acc);
        acc = fmaf(e.y, w.y, acc);
        acc = fmaf(e.z, w.z, acc);
        acc = fmaf(e.w, w.w, acc);
    }
    #pragma unroll
    for (int off = 32; off > 0; off >>= 1)
        acc += __shfl_down(acc, off);
    if (lane == 0) scores[b * T + t] = acc;
}

// Kernel 3: row softmax, one block of 1024 threads (16 waves) per b.
// One f4 per thread; wave shfl-reduce + LDS cross-wave reduce.
__global__ void __launch_bounds__(1024) softmax_kernel(
    const float* __restrict__ scores, float* __restrict__ out)
{
    int b = blockIdx.x;
    int tid = threadIdx.x;
    int wid = tid >> 6;
    int lane = tid & 63;
    __shared__ float redm[16];
    __shared__ float reds[16];

    const f4* rp = (const f4*)(scores + (size_t)b * T);
    f4 x = rp[tid];

    float m = fmaxf(fmaxf(x.x, x.y), fmaxf(x.z, x.w));
    #pragma unroll
    for (int off = 32; off > 0; off >>= 1)
        m = fmaxf(m, __shfl_xor(m, off));
    if (lane == 0) redm[wid] = m;
    __syncthreads();
    m = redm[0];
    #pragma unroll
    for (int i = 1; i < 16; ++i) m = fmaxf(m, redm[i]);

    x.x = __expf(x.x - m);
    x.y = __expf(x.y - m);
    x.z = __expf(x.z - m);
    x.w = __expf(x.w - m);
    float s = x.x + x.y + x.z + x.w;
    #pragma unroll
    for (int off = 32; off > 0; off >>= 1)
        s += __shfl_xor(s, off);
    if (lane == 0) reds[wid] = s;
    __syncthreads();
    s = reds[0];
    #pragma unroll
    for (int i = 1; i < 16; ++i) s += reds[i];
    float inv = 1.f / s;

    f4 r = x * inv;
    __builtin_nontemporal_store(r, (f4*)(out + (size_t)b * T) + tid);
}

extern "C" void kernel_launch(void* const* d_in, const int* in_sizes, int n_in,
                              void* d_out, int out_size, void* d_ws, size_t ws_size,
                              hipStream_t stream)
{
    const float* dec = (const float*)d_in[0];   // [H, B]
    const float* enc = (const float*)d_in[1];   // [T, B, H]
    const float* W   = (const float*)d_in[2];   // [H, H]
    float* out = (float*)d_out;                 // [B, T]

    float* v      = (float*)d_ws;               // B*H floats
    float* scores = v + B * H;                  // B*T floats

    proj_vec_kernel<<<512, 256, 0, stream>>>(dec, W, v);
    scores_kernel<<<(T * B) / 4, 256, 0, stream>>>(v, enc, scores);
    softmax_kernel<<<B, 1024, 0, stream>>>(scores, out);
}